// Round 6
// baseline (277.276 us; speedup 1.0000x reference)
//
#include <hip/hip_runtime.h>

// DynamicHead: varying-coefficient MLP, R6 = depth-4 B prefetch with 256-thread
// blocks (512-thread workgroups empirically cap VGPR at 128 -> R4/R5 spilled).
//   out[m,o] = sum_{s,i} (bas_s[m]*x[m,i]) * W[s,i,o] + sum_s bas_s[m]*b[s,o]
// Flat fp16 GEMM (K=3072), basis folded into A-frags at use (v_pk_mul_f16), single
// fp32 accumulator, B pre-packed in MFMA-frag order streamed from L2 via 4-deep
// register circular buffer, barrier-free K-loop.
// Block = 64 rows x 256 cols, 4 waves of 64x64 side by side (no A duplication).
// Grid 512 = exactly 2 blocks/CU (8 waves/CU).

typedef __attribute__((ext_vector_type(8))) _Float16 half8;
typedef __attribute__((ext_vector_type(4))) _Float16 half4;
typedef __attribute__((ext_vector_type(4))) float floatx4;

#define XPAD 264  // halves per LDS row: 256 + 8

__device__ __forceinline__ void make_basis(float t, float* p){
  p[0] = 1.f; p[1] = t; p[2] = t*t; p[3] = p[2]*t;
  const float knots[8] = {1.f/9.f, 2.f/9.f, 3.f/9.f, 4.f/9.f,
                          5.f/9.f, 6.f/9.f, 7.f/9.f, 8.f/9.f};
  #pragma unroll
  for (int j = 0; j < 8; ++j){
    float d = t - knots[j];
    d = fmaxf(d, 0.f);
    p[4+j] = d*d*d;
  }
}

// Pack W (12,256,256) fp32 -> f16 MFMA-B-frag order via LDS transpose.
// Wp[(κ*16+ntg)*512 + (q*16+n16)*8 + j] = f16(W[κ/8][(κ%8)*32+q*8+j][ntg*16+n16])
__global__ __launch_bounds__(256)
void pack_w_kernel(const float* __restrict__ W0, const float* __restrict__ W1,
                   _Float16* __restrict__ Wp0, _Float16* __restrict__ Wp1){
  __shared__ float wl[32 * 260];
  const int blk = blockIdx.x;
  const float* W = (blk < 96) ? W0 : W1;
  _Float16* Wp   = (blk < 96) ? Wp0 : Wp1;
  const int c    = (blk < 96) ? blk : blk - 96;   // κ
  const int tid  = threadIdx.x;
  const float* src = W + (size_t)c * 8192;        // 32 k-rows x 256 cols
  #pragma unroll
  for (int it = 0; it < 8; ++it){
    int idx = it * 256 + tid;          // float4 index 0..2047
    int r = idx >> 6, c4 = idx & 63;
    float4 v = *(const float4*)(src + (size_t)idx * 4);
    float* d = &wl[r * 260 + c4 * 4];
    d[0] = v.x; d[1] = v.y; d[2] = v.z; d[3] = v.w;
  }
  __syncthreads();
  _Float16* dst = Wp + (size_t)c * 8192;
  #pragma unroll
  for (int w = 0; w < 4; ++w){
    int v = w * 256 + tid;             // 0..1023
    int n16 = v & 15, qq = (v >> 4) & 3, ntg = v >> 6;
    half8 o;
    #pragma unroll
    for (int j = 0; j < 8; ++j)
      o[j] = (_Float16)wl[(qq * 8 + j) * 260 + ntg * 16 + n16];
    *(half8*)(dst + (size_t)v * 8) = o;
  }
}

// Block: 64 rows x 256 cols, 256 threads = 4 waves, wave wid covers cols wid*64..+64.
// Grid: 512 blocks -> 2 blocks/CU. Barrier-free K-loop; B prefetch depth 4.
template<bool IN_F32>
__global__ __launch_bounds__(256, 2)
void layer_kernel(const void* __restrict__ in_v, const float* __restrict__ treat,
                  const _Float16* __restrict__ Wp, const float* __restrict__ bias,
                  _Float16* __restrict__ out){
  __shared__ _Float16 Xl[64 * XPAD];    // 33,792 B
  __shared__ float blds[12 * 64];       // 3,072 B

  const int tid  = threadIdx.x;
  const int m0   = blockIdx.x * 64;
  const int lane = tid & 63;
  const int wn   = tid >> 6;            // 0..3: cols wn*64..+64
  const int q    = lane >> 4;
  const int l16  = lane & 15;

  // ---- B preload (depth 4) issued FIRST so it overlaps X staging ----
  const _Float16* wb = Wp + wn * 2048 + lane * 8;
  half8 bbuf[4][4];
  #pragma unroll
  for (int d = 0; d < 4; ++d)
    #pragma unroll
    for (int nt = 0; nt < 4; ++nt)
      bbuf[d][nt] = *(const half8*)(wb + (size_t)d * 8192 + nt * 512);
  wb += 4 * 8192;

  // ---- stage X tile (64 x 256) into LDS as f16 ----
  if (IN_F32){
    const float* X = (const float*)in_v;
    #pragma unroll
    for (int it = 0; it < 16; ++it){
      int idx = it * 256 + tid;          // 4096 float4 chunks
      int m = idx >> 6, c = idx & 63;
      float4 v = *(const float4*)(X + (size_t)(m0 + m) * 256 + c * 4);
      half4 h = { (_Float16)v.x, (_Float16)v.y, (_Float16)v.z, (_Float16)v.w };
      *(half4*)&Xl[m * XPAD + c * 4] = h;
    }
  } else {
    const _Float16* X = (const _Float16*)in_v;
    #pragma unroll
    for (int it = 0; it < 8; ++it){
      int idx = it * 256 + tid;          // 2048 half8 chunks
      int m = idx >> 5, c = idx & 31;
      half8 v = *(const half8*)(X + (size_t)(m0 + m) * 256 + c * 8);
      *(half8*)&Xl[m * XPAD + c * 8] = v;
    }
  }
  if (tid < 64){
    float t = treat[m0 + tid];
    float p[12]; make_basis(t, p);
    #pragma unroll
    for (int s = 0; s < 12; ++s) blds[s * 64 + tid] = p[s];
  }
  __syncthreads();

  // A frag: row = mt*16 + l16, k = ko*32 + q*8 + j
  const unsigned xbase = (unsigned)l16 * XPAD + q * 8;

  const floatx4 zero = {0.f, 0.f, 0.f, 0.f};
  floatx4 acc[4][4];
  #pragma unroll
  for (int mt = 0; mt < 4; ++mt)
    #pragma unroll
    for (int nt = 0; nt < 4; ++nt) acc[mt][nt] = zero;

  half8 xc[4], xn[4];
  #pragma unroll
  for (int mt = 0; mt < 4; ++mt)
    xc[mt] = *(const half8*)&Xl[xbase + mt * 16 * XPAD];

  for (int s = 0; s < 12; ++s){
    _Float16 bash[4];
    #pragma unroll
    for (int mt = 0; mt < 4; ++mt)
      bash[mt] = (_Float16)blds[s * 64 + mt * 16 + l16];

    #pragma unroll
    for (int ko = 0; ko < 8; ++ko){
      const int ph   = ko & 3;
      const int ko_n = (ko + 1) & 7;
      // A prefetch (distance 1; wraps at s boundary — always a valid LDS read)
      #pragma unroll
      for (int mt = 0; mt < 4; ++mt)
        xn[mt] = *(const half8*)&Xl[xbase + mt * 16 * XPAD + ko_n * 32];
      // basis-scaled A (v_pk_mul_f16)
      half8 az[4];
      #pragma unroll
      for (int mt = 0; mt < 4; ++mt) az[mt] = xc[mt] * bash[mt];
      // consume bbuf[ph] in MFMAs, then refill the slot (4 ksteps ahead).
      // (tail prefetches read past Wp into adjacent workspace — valid, unused)
      #pragma unroll
      for (int nt = 0; nt < 4; ++nt){
        #pragma unroll
        for (int mt = 0; mt < 4; ++mt)
          acc[mt][nt] = __builtin_amdgcn_mfma_f32_16x16x32_f16(
              az[mt], bbuf[ph][nt], acc[mt][nt], 0, 0, 0);
        bbuf[ph][nt] = *(const half8*)(wb + nt * 512);
      }
      wb += 8192;
      #pragma unroll
      for (int mt = 0; mt < 4; ++mt) xc[mt] = xn[mt];
    }
  }

  // ---- epilogue: + sum_s bas_s*b[s,o], relu, f16 store ----
  for (int s = 0; s < 12; ++s){
    float bl[4];
    #pragma unroll
    for (int nt = 0; nt < 4; ++nt)
      bl[nt] = bias[s * 256 + wn * 64 + nt * 16 + l16];
    floatx4 bs[4];
    #pragma unroll
    for (int mt = 0; mt < 4; ++mt)
      bs[mt] = *(const floatx4*)&blds[s * 64 + mt * 16 + q * 4];
    #pragma unroll
    for (int mt = 0; mt < 4; ++mt)
      #pragma unroll
      for (int nt = 0; nt < 4; ++nt)
        #pragma unroll
        for (int r = 0; r < 4; ++r)
          acc[mt][nt][r] += bs[mt][r] * bl[nt];
  }
  // C/D layout: col = lane&15, row = (lane>>4)*4 + reg
  #pragma unroll
  for (int mt = 0; mt < 4; ++mt){
    #pragma unroll
    for (int nt = 0; nt < 4; ++nt){
      int col = wn * 64 + nt * 16 + l16;
      #pragma unroll
      for (int r = 0; r < 4; ++r){
        int row = m0 + mt * 16 + q * 4 + r;
        out[(size_t)row * 256 + col] = (_Float16)fmaxf(acc[mt][nt][r], 0.f);
      }
    }
  }
}

// Final layer (out dim 1): one wave per 4 rows, W2 staged in LDS. 2048 blocks.
__global__ __launch_bounds__(256)
void final_kernel(const _Float16* __restrict__ X2, const float* __restrict__ treat,
                  const float* __restrict__ W2, const float* __restrict__ b2,
                  float* __restrict__ out){
  __shared__ float w2l[12 * 256];
  __shared__ float b2l[12];
  const int tid = threadIdx.x;
  const int m0 = blockIdx.x * 16;
  #pragma unroll
  for (int it = 0; it < 12; ++it) w2l[it * 256 + tid] = W2[it * 256 + tid];
  if (tid < 12) b2l[tid] = b2[tid];
  __syncthreads();
  const int lane = tid & 63, wid = tid >> 6;
  #pragma unroll
  for (int rr = 0; rr < 4; ++rr){
    int b = m0 + wid * 4 + rr;
    float t = treat[b];
    float p[12]; make_basis(t, p);
    half4 xv = *(const half4*)(X2 + (size_t)b * 256 + lane * 4);
    float xs[4] = { (float)xv.x, (float)xv.y, (float)xv.z, (float)xv.w };
    float ws[4] = {0.f, 0.f, 0.f, 0.f};
    #pragma unroll
    for (int s = 0; s < 12; ++s){
      floatx4 w4 = *(const floatx4*)&w2l[s * 256 + lane * 4];
      #pragma unroll
      for (int j = 0; j < 4; ++j) ws[j] += p[s] * w4[j];
    }
    float dot = xs[0]*ws[0] + xs[1]*ws[1] + xs[2]*ws[2] + xs[3]*ws[3];
    #pragma unroll
    for (int off = 32; off > 0; off >>= 1) dot += __shfl_down(dot, off, 64);
    if (lane == 0){
      float bb = 0.f;
      #pragma unroll
      for (int s = 0; s < 12; ++s) bb += p[s] * b2l[s];
      out[b] = dot + bb;
    }
  }
}

extern "C" void kernel_launch(void* const* d_in, const int* in_sizes, int n_in,
                              void* d_out, int out_size, void* d_ws, size_t ws_size,
                              hipStream_t stream){
  const float* treat = (const float*)d_in[0];
  const float* feat  = (const float*)d_in[1];
  const float* W0    = (const float*)d_in[2];
  const float* b0    = (const float*)d_in[3];
  const float* W1    = (const float*)d_in[4];
  const float* b1    = (const float*)d_in[5];
  const float* W2    = (const float*)d_in[6];
  const float* b2    = (const float*)d_in[7];

  char* ws = (char*)d_ws;
  _Float16* Wp0 = (_Float16*)(ws);                     // 1,572,864 B
  _Float16* Wp1 = (_Float16*)(ws + 1572864);           // 1,572,864 B
  _Float16* X1  = (_Float16*)(ws + 3145728);           // 16,777,216 B
  _Float16* X2  = (_Float16*)(ws + 19922944);          // 16,777,216 B
  float* out = (float*)d_out;

  pack_w_kernel<<<192, 256, 0, stream>>>(W0, W1, Wp0, Wp1);
  layer_kernel<true ><<<512, 256, 0, stream>>>((const void*)feat, treat, Wp0, b0, X1);
  layer_kernel<false><<<512, 256, 0, stream>>>((const void*)X1,  treat, Wp1, b1, X2);
  final_kernel<<<2048, 256, 0, stream>>>(X2, treat, W2, b2, out);
}

// Round 7
// 220.044 us; speedup vs baseline: 1.2601x; 1.2601x over previous
//
#include <hip/hip_runtime.h>

// DynamicHead: varying-coefficient MLP, R7 = R3 structure + depth-2/distance-2
// circular B prefetch (fits the empirical ~128 arch-VGPR cap; R4-R6's depth-4
// needed ~152 and spilled catastrophically in every workgroup shape).
//   out[m,o] = sum_{s,i} (bas_s[m]*x[m,i]) * W[s,i,o] + sum_s bas_s[m]*b[s,o]
// Flat fp16 GEMM (K=3072), basis folded into A-frags at use (v_pk_mul_f16), single
// fp32 accumulator (AGPRs), B pre-packed in MFMA-frag order streamed from L2.
// Block = 128 rows x 256 cols, 8 waves of 64x64, grid 256 = 1 block/CU.

typedef __attribute__((ext_vector_type(8))) _Float16 half8;
typedef __attribute__((ext_vector_type(4))) _Float16 half4;
typedef __attribute__((ext_vector_type(4))) float floatx4;

#define XPAD 264  // halves per LDS row: 256 + 8

__device__ __forceinline__ void make_basis(float t, float* p){
  p[0] = 1.f; p[1] = t; p[2] = t*t; p[3] = p[2]*t;
  const float knots[8] = {1.f/9.f, 2.f/9.f, 3.f/9.f, 4.f/9.f,
                          5.f/9.f, 6.f/9.f, 7.f/9.f, 8.f/9.f};
  #pragma unroll
  for (int j = 0; j < 8; ++j){
    float d = t - knots[j];
    d = fmaxf(d, 0.f);
    p[4+j] = d*d*d;
  }
}

// Pack W (12,256,256) fp32 -> f16 MFMA-B-frag order via LDS transpose.
// Wp[(κ*16+ntg)*512 + (q*16+n16)*8 + j] = f16(W[κ/8][(κ%8)*32+q*8+j][ntg*16+n16])
__global__ __launch_bounds__(256)
void pack_w_kernel(const float* __restrict__ W0, const float* __restrict__ W1,
                   _Float16* __restrict__ Wp0, _Float16* __restrict__ Wp1){
  __shared__ float wl[32 * 260];
  const int blk = blockIdx.x;
  const float* W = (blk < 96) ? W0 : W1;
  _Float16* Wp   = (blk < 96) ? Wp0 : Wp1;
  const int c    = (blk < 96) ? blk : blk - 96;   // κ
  const int tid  = threadIdx.x;
  const float* src = W + (size_t)c * 8192;        // 32 k-rows x 256 cols
  #pragma unroll
  for (int it = 0; it < 8; ++it){
    int idx = it * 256 + tid;          // float4 index 0..2047
    int r = idx >> 6, c4 = idx & 63;
    float4 v = *(const float4*)(src + (size_t)idx * 4);
    float* d = &wl[r * 260 + c4 * 4];
    d[0] = v.x; d[1] = v.y; d[2] = v.z; d[3] = v.w;
  }
  __syncthreads();
  _Float16* dst = Wp + (size_t)c * 8192;
  #pragma unroll
  for (int w = 0; w < 4; ++w){
    int v = w * 256 + tid;             // 0..1023
    int n16 = v & 15, qq = (v >> 4) & 3, ntg = v >> 6;
    half8 o;
    #pragma unroll
    for (int j = 0; j < 8; ++j)
      o[j] = (_Float16)wl[(qq * 8 + j) * 260 + ntg * 16 + n16];
    *(half8*)(dst + (size_t)v * 8) = o;
  }
}

// Block: 128 rows x 256 cols, 512 threads = 8 waves as 2(m) x 4(n) of 64x64.
// Grid: 256 blocks -> 1 block/CU. Barrier-free K-loop; B circular depth 2, dist 2.
template<bool IN_F32>
__global__ __launch_bounds__(512, 2)
void layer_kernel(const void* __restrict__ in_v, const float* __restrict__ treat,
                  const _Float16* __restrict__ Wp, const float* __restrict__ bias,
                  _Float16* __restrict__ out){
  __shared__ _Float16 Xl[128 * XPAD];   // 67,584 B
  __shared__ float blds[12 * 128];      // 6,144 B

  const int tid  = threadIdx.x;
  const int m0   = blockIdx.x * 128;
  const int lane = tid & 63;
  const int wid  = tid >> 6;
  const int wm   = wid >> 2;            // 0..1: rows wm*64..+64
  const int wn   = wid & 3;             // 0..3: cols wn*64..+64
  const int q    = lane >> 4;
  const int l16  = lane & 15;

  // ---- B preload (slots for ksteps 0,1) issued FIRST: overlaps X staging ----
  const _Float16* wb = Wp + wn * 2048 + lane * 8;
  half8 bbuf[2][4];
  #pragma unroll
  for (int d = 0; d < 2; ++d)
    #pragma unroll
    for (int nt = 0; nt < 4; ++nt)
      bbuf[d][nt] = *(const half8*)(wb + (size_t)d * 8192 + nt * 512);
  wb += 2 * 8192;

  // ---- stage X tile (128 x 256) into LDS as f16 ----
  if (IN_F32){
    const float* X = (const float*)in_v;
    #pragma unroll
    for (int it = 0; it < 16; ++it){
      int idx = it * 512 + tid;          // 8192 float4 chunks
      int m = idx >> 6, c = idx & 63;
      float4 v = *(const float4*)(X + (size_t)(m0 + m) * 256 + c * 4);
      half4 h = { (_Float16)v.x, (_Float16)v.y, (_Float16)v.z, (_Float16)v.w };
      *(half4*)&Xl[m * XPAD + c * 4] = h;
    }
  } else {
    const _Float16* X = (const _Float16*)in_v;
    #pragma unroll
    for (int it = 0; it < 8; ++it){
      int idx = it * 512 + tid;          // 4096 half8 chunks
      int m = idx >> 5, c = idx & 31;
      half8 v = *(const half8*)(X + (size_t)(m0 + m) * 256 + c * 8);
      *(half8*)&Xl[m * XPAD + c * 8] = v;
    }
  }
  if (tid < 128){
    float t = treat[m0 + tid];
    float p[12]; make_basis(t, p);
    #pragma unroll
    for (int s = 0; s < 12; ++s) blds[s * 128 + tid] = p[s];
  }
  __syncthreads();

  // A frag: row = wm*64 + mt*16 + l16, k = ko*32 + q*8 + j
  const unsigned xbase = (unsigned)(wm * 64 + l16) * XPAD + q * 8;

  const floatx4 zero = {0.f, 0.f, 0.f, 0.f};
  floatx4 acc[4][4];
  #pragma unroll
  for (int mt = 0; mt < 4; ++mt)
    #pragma unroll
    for (int nt = 0; nt < 4; ++nt) acc[mt][nt] = zero;

  half8 xc[4], xn[4];
  #pragma unroll
  for (int mt = 0; mt < 4; ++mt)
    xc[mt] = *(const half8*)&Xl[xbase + mt * 16 * XPAD];

  for (int s = 0; s < 12; ++s){
    _Float16 bash[4];
    #pragma unroll
    for (int mt = 0; mt < 4; ++mt)
      bash[mt] = (_Float16)blds[s * 128 + wm * 64 + mt * 16 + l16];

    #pragma unroll
    for (int ko = 0; ko < 8; ++ko){
      const int ph   = ko & 1;           // compile-time after unroll
      const int ko_n = (ko + 1) & 7;
      // A prefetch (distance 1; wraps at s boundary — A frags are s-independent)
      #pragma unroll
      for (int mt = 0; mt < 4; ++mt)
        xn[mt] = *(const half8*)&Xl[xbase + mt * 16 * XPAD + ko_n * 32];
      // basis-scaled A (v_pk_mul_f16)
      half8 az[4];
      #pragma unroll
      for (int mt = 0; mt < 4; ++mt) az[mt] = xc[mt] * bash[mt];
      // consume bbuf[ph]; refill the slot with kstep+2's frags (distance 2).
      // Per-nt interleave: 4 MFMAs then 1 load. Tail refills read past Wp into
      // adjacent workspace — valid memory, values unused.
      #pragma unroll
      for (int nt = 0; nt < 4; ++nt){
        #pragma unroll
        for (int mt = 0; mt < 4; ++mt)
          acc[mt][nt] = __builtin_amdgcn_mfma_f32_16x16x32_f16(
              az[mt], bbuf[ph][nt], acc[mt][nt], 0, 0, 0);
        bbuf[ph][nt] = *(const half8*)(wb + nt * 512);
      }
      wb += 8192;
      #pragma unroll
      for (int mt = 0; mt < 4; ++mt) xc[mt] = xn[mt];
    }
  }

  // ---- epilogue: + sum_s bas_s*b[s,o], relu, f16 store ----
  for (int s = 0; s < 12; ++s){
    float bl[4];
    #pragma unroll
    for (int nt = 0; nt < 4; ++nt)
      bl[nt] = bias[s * 256 + wn * 64 + nt * 16 + l16];
    floatx4 bs[4];
    #pragma unroll
    for (int mt = 0; mt < 4; ++mt)
      bs[mt] = *(const floatx4*)&blds[s * 128 + wm * 64 + mt * 16 + q * 4];
    #pragma unroll
    for (int mt = 0; mt < 4; ++mt)
      #pragma unroll
      for (int nt = 0; nt < 4; ++nt)
        #pragma unroll
        for (int r = 0; r < 4; ++r)
          acc[mt][nt][r] += bs[mt][r] * bl[nt];
  }
  // C/D layout: col = lane&15, row = (lane>>4)*4 + reg
  #pragma unroll
  for (int mt = 0; mt < 4; ++mt){
    #pragma unroll
    for (int nt = 0; nt < 4; ++nt){
      int col = wn * 64 + nt * 16 + l16;
      #pragma unroll
      for (int r = 0; r < 4; ++r){
        int row = m0 + wm * 64 + mt * 16 + q * 4 + r;
        out[(size_t)row * 256 + col] = (_Float16)fmaxf(acc[mt][nt][r], 0.f);
      }
    }
  }
}

// Final layer (out dim 1): one wave per 4 rows, W2 staged in LDS. 2048 blocks.
__global__ __launch_bounds__(256)
void final_kernel(const _Float16* __restrict__ X2, const float* __restrict__ treat,
                  const float* __restrict__ W2, const float* __restrict__ b2,
                  float* __restrict__ out){
  __shared__ float w2l[12 * 256];
  __shared__ float b2l[12];
  const int tid = threadIdx.x;
  const int m0 = blockIdx.x * 16;
  #pragma unroll
  for (int it = 0; it < 12; ++it) w2l[it * 256 + tid] = W2[it * 256 + tid];
  if (tid < 12) b2l[tid] = b2[tid];
  __syncthreads();
  const int lane = tid & 63, wid = tid >> 6;
  #pragma unroll
  for (int rr = 0; rr < 4; ++rr){
    int b = m0 + wid * 4 + rr;
    float t = treat[b];
    float p[12]; make_basis(t, p);
    half4 xv = *(const half4*)(X2 + (size_t)b * 256 + lane * 4);
    float xs[4] = { (float)xv.x, (float)xv.y, (float)xv.z, (float)xv.w };
    float ws[4] = {0.f, 0.f, 0.f, 0.f};
    #pragma unroll
    for (int s = 0; s < 12; ++s){
      floatx4 w4 = *(const floatx4*)&w2l[s * 256 + lane * 4];
      #pragma unroll
      for (int j = 0; j < 4; ++j) ws[j] += p[s] * w4[j];
    }
    float dot = xs[0]*ws[0] + xs[1]*ws[1] + xs[2]*ws[2] + xs[3]*ws[3];
    #pragma unroll
    for (int off = 32; off > 0; off >>= 1) dot += __shfl_down(dot, off, 64);
    if (lane == 0){
      float bb = 0.f;
      #pragma unroll
      for (int s = 0; s < 12; ++s) bb += p[s] * b2l[s];
      out[b] = dot + bb;
    }
  }
}

extern "C" void kernel_launch(void* const* d_in, const int* in_sizes, int n_in,
                              void* d_out, int out_size, void* d_ws, size_t ws_size,
                              hipStream_t stream){
  const float* treat = (const float*)d_in[0];
  const float* feat  = (const float*)d_in[1];
  const float* W0    = (const float*)d_in[2];
  const float* b0    = (const float*)d_in[3];
  const float* W1    = (const float*)d_in[4];
  const float* b1    = (const float*)d_in[5];
  const float* W2    = (const float*)d_in[6];
  const float* b2    = (const float*)d_in[7];

  char* ws = (char*)d_ws;
  _Float16* Wp0 = (_Float16*)(ws);                     // 1,572,864 B
  _Float16* Wp1 = (_Float16*)(ws + 1572864);           // 1,572,864 B
  _Float16* X1  = (_Float16*)(ws + 3145728);           // 16,777,216 B
  _Float16* X2  = (_Float16*)(ws + 19922944);          // 16,777,216 B
  float* out = (float*)d_out;

  pack_w_kernel<<<192, 256, 0, stream>>>(W0, W1, Wp0, Wp1);
  layer_kernel<true ><<<256, 512, 0, stream>>>((const void*)feat, treat, Wp0, b0, X1);
  layer_kernel<false><<<256, 512, 0, stream>>>((const void*)X1,  treat, Wp1, b1, X2);
  final_kernel<<<2048, 256, 0, stream>>>(X2, treat, W2, b2, out);
}